// Round 12
// baseline (221.093 us; speedup 1.0000x reference)
//
#include <hip/hip_runtime.h>

typedef __attribute__((ext_vector_type(4))) float float4v;
typedef __attribute__((ext_vector_type(8))) short short8;
typedef __attribute__((ext_vector_type(16))) float f32x16;

#define C_IN 32
#define C_OUT 32
#define HH 224
#define WW 224
#define HW (HH * WW)
#define STRIPE 14                 // output rows per block; 224 = 16 stripes x 32 imgs = 512 blocks
#define RING_PX 226               // w = -1 .. 224 (halo columns at px 0 and 225)
#define PIX_STRIDE 80             // 64B data (32ch bf16) + 16B pad; conflict-free b128
#define ROW_BYTES (RING_PX * PIX_STRIDE)  // 18,080
#define NTHR 512

// fp32 -> bf16 bits, round-to-nearest-even
__device__ __forceinline__ short f2bf(float f) {
    unsigned u = __float_as_uint(f);
    u += 0x7FFFu + ((u >> 16) & 1u);
    return (short)(u >> 16);
}
// pack two bf16 (even ch in low half) into one dword
__device__ __forceinline__ unsigned pack2(float e, float o) {
    return (unsigned)(unsigned short)f2bf(e) | ((unsigned)(unsigned short)f2bf(o) << 16);
}

// R12 = R7's known-correct kernel; occupancy knob changed to the one that
// demonstrably works. VGPR-cap history: launch_bounds(256,5)->48 (R2 spill),
// (512,4)->64 (R11 spill); amdgpu_waves_per_eu(2,2)->cap 256, clean 116 (R6).
// waves_per_eu(4,4): cap 512/4 = 128 >= 116 need -> clean codegen at exactly
// 4 waves/SIMD = 16 waves/CU = 2 co-resident blocks (LDS 2x54.2KB = 108.5KB).
// This is the clean TLP test R7/R11 both failed to run.
__global__ __launch_bounds__(NTHR) __attribute__((amdgpu_waves_per_eu(4, 4)))
void conv3x3_rows(const float* __restrict__ X, const float* __restrict__ Wt,
                  const float* __restrict__ Bias, float* __restrict__ Y) {
    __shared__ __align__(16) char ring0[ROW_BYTES];
    __shared__ __align__(16) char ring1[ROW_BYTES];
    __shared__ __align__(16) char ring2[ROW_BYTES];   // 54,240 B total

    const int tid = threadIdx.x;
    const int lane = tid & 63;
    const int wid = tid >> 6;      // wave 0..7
    const int col = lane & 31;     // A: out-channel; B/C: pixel col
    const int khalf = lane >> 5;   // K-half of MFMA K=16 slice

    // --- W fragments (A operand: M=32 k_out, K=16 c-slice) ---
    short8 wfrag[18];
#pragma unroll
    for (int rs = 0; rs < 9; ++rs) {
#pragma unroll
        for (int ch = 0; ch < 2; ++ch) {
            short8 f;
#pragma unroll
            for (int j = 0; j < 8; ++j) {
                int c = ch * 16 + khalf * 8 + j;
                f[j] = f2bf(Wt[(col * C_IN + c) * 9 + rs]);  // W[k_out][c][r][s]
            }
            wfrag[rs * 2 + ch] = f;
        }
    }

    // --- Bias in C-fragment order: row(k_out) = (i&3) + 8*(i>>2) + 4*khalf ---
    f32x16 biasv;
#pragma unroll
    for (int i = 0; i < 16; ++i)
        biasv[i] = Bias[(i & 3) + 8 * (i >> 2) + 4 * khalf];

    // --- Staging geometry: unit u = w4*16 + cp (cp = channel-pair, w4 = 4px group) ---
    const int cp0 = tid & 15, w40 = tid >> 4;         // unit0 = tid (896 units total)
    const int t1 = tid + NTHR;
    const bool has1 = (tid < 896 - NTHR);             // threads 0..383 take a second unit
    const int cp1 = t1 & 15, w41 = t1 >> 4;
    const int ge0 = (2 * cp0) * HW + 4 * w40;         // float offsets from (n, hh) row base
    const int go0 = ge0 + HW;
    const int ge1 = (2 * cp1) * HW + 4 * w41;
    const int go1 = ge1 + HW;

    const int bid = blockIdx.x;
    const int n = bid >> 4;                // image
    const int h1 = (bid & 15) * STRIPE;    // stripe start row
    const float* Xn = X + n * C_IN * HW;

    float4v e0, o0, e1, o1;
    const short8 z8 = {0, 0, 0, 0, 0, 0, 0, 0};

#define LOAD_ROW(hh) do {                                          \
        const float* rp = Xn + (hh) * WW;                          \
        e0 = *(const float4v*)(rp + ge0);                          \
        o0 = *(const float4v*)(rp + go0);                          \
        if (has1) {                                                \
            e1 = *(const float4v*)(rp + ge1);                      \
            o1 = *(const float4v*)(rp + go1);                      \
        }                                                          \
    } while (0)

#define WRITE_ROW(sb) do {                                         \
        char* wb0 = (sb) + (1 + 4 * w40) * PIX_STRIDE + cp0 * 4;   \
        *(unsigned*)(wb0                  ) = pack2(e0[0], o0[0]); \
        *(unsigned*)(wb0 +     PIX_STRIDE ) = pack2(e0[1], o0[1]); \
        *(unsigned*)(wb0 + 2 * PIX_STRIDE ) = pack2(e0[2], o0[2]); \
        *(unsigned*)(wb0 + 3 * PIX_STRIDE ) = pack2(e0[3], o0[3]); \
        if (has1) {                                                \
            char* wb1 = (sb) + (1 + 4 * w41) * PIX_STRIDE + cp1 * 4; \
            *(unsigned*)(wb1                  ) = pack2(e1[0], o1[0]); \
            *(unsigned*)(wb1 +     PIX_STRIDE ) = pack2(e1[1], o1[1]); \
            *(unsigned*)(wb1 + 2 * PIX_STRIDE ) = pack2(e1[2], o1[2]); \
            *(unsigned*)(wb1 + 3 * PIX_STRIDE ) = pack2(e1[3], o1[3]); \
        }                                                          \
        if (tid < 8) {  /* zero the two w-halo pixels (px 0 and 225) */ \
            int px = (tid < 4) ? 0 : (RING_PX - 1);                \
            *(short8*)((sb) + px * PIX_STRIDE + (tid & 3) * 16) = z8; \
        }                                                          \
    } while (0)

#define ZERO_ROW(sb) do {                                          \
        for (int i = tid; i < ROW_BYTES / 16; i += NTHR)           \
            *(short8*)((sb) + i * 16) = z8;                        \
    } while (0)

    // ===== Prologue: fill ring with rows h1-1, h1, h1+1 =====
#pragma unroll
    for (int j = 0; j < 3; ++j) {
        int hh = h1 - 1 + j;
        char* sb = (j == 0) ? ring0 : (j == 1) ? ring1 : ring2;
        if (hh >= 0 && hh < HH) {   // block-uniform
            LOAD_ROW(hh);
            WRITE_ROW(sb);
        } else {
            ZERO_ROW(sb);
        }
    }
    __syncthreads();

    // ===== Main loop: rA = row h-1, rB = h, rC = h+1; write h+2 over rA =====
    char *rA = ring0, *rB = ring1, *rC = ring2;
    const int pcol = col * PIX_STRIDE + khalf * 16;

    for (int h = h1; h < h1 + STRIPE; ++h) {
        const int hh = h + 2;
        const bool do_pref = (hh <= h1 + STRIPE);   // last needed row = h1+STRIPE
        const bool validrow = do_pref && (hh < HH); // block-uniform

        // Phase 1: issue next row's global loads (waits land in Phase 4, after MFMA)
        if (validrow) LOAD_ROW(hh);

        // Phase 2: compute output row h; wave w owns px [32w, 32w+32)
        if (wid < 7) {
            const int px0 = wid * 32;
            f32x16 acc = biasv;   // bias folded into accumulator init
            const int pb = px0 * PIX_STRIDE + pcol;
#pragma unroll
            for (int rs = 0; rs < 9; ++rs) {
                const int r = rs / 3, s = rs - 3 * r;
                const char* rb = (r == 0) ? rA : (r == 1) ? rB : rC;
                const int addr = pb + s * PIX_STRIDE;
#pragma unroll
                for (int ch = 0; ch < 2; ++ch) {
                    short8 bfrag = *(const short8*)(rb + addr + ch * 32);
                    acc = __builtin_amdgcn_mfma_f32_32x32x16_bf16(
                        wfrag[rs * 2 + ch], bfrag, acc, 0, 0, 0);
                }
            }
            const int ybase = n * C_OUT * HW + h * WW + px0 + col;
#pragma unroll
            for (int i = 0; i < 16; ++i) {
                int ko = (i & 3) + 8 * (i >> 2) + 4 * khalf;
                Y[ybase + ko * HW] = acc[i];
            }
        }

        // Phase 3: all reads of rA done before it is overwritten
        __syncthreads();

        // Phase 4: convert + write row h+2 into the expired slot
        if (validrow) {
            WRITE_ROW(rA);
        } else if (do_pref) {
            ZERO_ROW(rA);   // image bottom edge
        }
        __syncthreads();

        // rotate ring
        char* t = rA; rA = rB; rB = rC; rC = t;
    }
#undef LOAD_ROW
#undef WRITE_ROW
#undef ZERO_ROW
}

extern "C" void kernel_launch(void* const* d_in, const int* in_sizes, int n_in,
                              void* d_out, int out_size, void* d_ws, size_t ws_size,
                              hipStream_t stream) {
    const float* X = (const float*)d_in[0];
    const float* W = (const float*)d_in[1];
    const float* B = (const float*)d_in[2];
    float* Y = (float*)d_out;
    // 512 blocks = 32 images x 16 stripes; 2 resident per CU (LDS 108.5KB/CU)
    conv3x3_rows<<<dim3(512), dim3(NTHR), 0, stream>>>(X, W, B, Y);
}

// Round 13
// 102.427 us; speedup vs baseline: 2.1585x; 2.1585x over previous
//
#include <hip/hip_runtime.h>

typedef __attribute__((ext_vector_type(4))) float float4v;
typedef __attribute__((ext_vector_type(8))) short short8;
typedef __attribute__((ext_vector_type(16))) float f32x16;

#define C_IN 32
#define C_OUT 32
#define HH 224
#define WW 224
#define HW (HH * WW)
#define STRIPE 28                 // output rows per block; 8 stripes x 32 imgs = 256 blocks
#define RING_PX 226               // w = -1 .. 224 (halo columns at px 0 and 225)
#define PIX_STRIDE 80             // 64B data (32ch bf16) + 16B pad; conflict-free b128
#define ROW_BYTES (RING_PX * PIX_STRIDE)  // 18,080
#define NTHR 512

// fp32 -> bf16 bits, round-to-nearest-even
__device__ __forceinline__ short f2bf(float f) {
    unsigned u = __float_as_uint(f);
    u += 0x7FFFu + ((u >> 16) & 1u);
    return (short)(u >> 16);
}
// pack two bf16 (even ch in low half) into one dword
__device__ __forceinline__ unsigned pack2(float e, float o) {
    return (unsigned)(unsigned short)f2bf(e) | ((unsigned)(unsigned short)f2bf(o) << 16);
}

// Raw barrier: LDS-visibility only (lgkmcnt), NO vmcnt(0) drain. __syncthreads
// compiles to s_waitcnt vmcnt(0) lgkmcnt(0); at 1 block/CU that stalls every
// row-step on Y-store ACKs (~1-3k cy) that nothing needs — Y is write-only,
// prefetch-load deps are compiler-tracked dataflow. T4: never drain vmcnt to 0
// in the main loop.
#define BAR() do {                                             \
        asm volatile("s_waitcnt lgkmcnt(0)" ::: "memory");     \
        __builtin_amdgcn_s_barrier();                          \
    } while (0)

// R13 = R6's known-correct kernel (103 us, clean 116-VGPR codegen at
// waves_per_eu(2,2)) with ONE change: main-loop __syncthreads() -> BAR().
// R12 closed the TLP door: 4 waves/EU => 128-reg unified VGPR+AGPR budget,
// kernel needs ~150 -> unavoidable spill. So cut the stall instead of adding waves.
__global__ __launch_bounds__(NTHR) __attribute__((amdgpu_waves_per_eu(2, 2)))
void conv3x3_rows(const float* __restrict__ X, const float* __restrict__ Wt,
                  const float* __restrict__ Bias, float* __restrict__ Y) {
    __shared__ __align__(16) char ring0[ROW_BYTES];
    __shared__ __align__(16) char ring1[ROW_BYTES];
    __shared__ __align__(16) char ring2[ROW_BYTES];   // 54,240 B total

    const int tid = threadIdx.x;
    const int lane = tid & 63;
    const int wid = tid >> 6;      // wave 0..7
    const int col = lane & 31;     // A: out-channel; B/C: pixel col
    const int khalf = lane >> 5;   // K-half of MFMA K=16 slice

    // --- W fragments (A operand: M=32 k_out, K=16 c-slice) ---
    short8 wfrag[18];
#pragma unroll
    for (int rs = 0; rs < 9; ++rs) {
#pragma unroll
        for (int ch = 0; ch < 2; ++ch) {
            short8 f;
#pragma unroll
            for (int j = 0; j < 8; ++j) {
                int c = ch * 16 + khalf * 8 + j;
                f[j] = f2bf(Wt[(col * C_IN + c) * 9 + rs]);  // W[k_out][c][r][s]
            }
            wfrag[rs * 2 + ch] = f;
        }
    }

    // --- Bias in C-fragment order: row(k_out) = (i&3) + 8*(i>>2) + 4*khalf ---
    f32x16 biasv;
#pragma unroll
    for (int i = 0; i < 16; ++i)
        biasv[i] = Bias[(i & 3) + 8 * (i >> 2) + 4 * khalf];

    // --- Staging geometry: unit u = w4*16 + cp (cp = channel-pair, w4 = 4px group) ---
    const int cp0 = tid & 15, w40 = tid >> 4;         // unit0 = tid (896 units total)
    const int t1 = tid + NTHR;
    const bool has1 = (tid < 896 - NTHR);             // threads 0..383 take a second unit
    const int cp1 = t1 & 15, w41 = t1 >> 4;
    const int ge0 = (2 * cp0) * HW + 4 * w40;         // float offsets from (n, hh) row base
    const int go0 = ge0 + HW;
    const int ge1 = (2 * cp1) * HW + 4 * w41;
    const int go1 = ge1 + HW;

    const int bid = blockIdx.x;
    const int n = bid >> 3;
    const int h1 = (bid & 7) * STRIPE;
    const float* Xn = X + n * C_IN * HW;

    float4v e0, o0, e1, o1;
    const short8 z8 = {0, 0, 0, 0, 0, 0, 0, 0};

#define LOAD_ROW(hh) do {                                          \
        const float* rp = Xn + (hh) * WW;                          \
        e0 = *(const float4v*)(rp + ge0);                          \
        o0 = *(const float4v*)(rp + go0);                          \
        if (has1) {                                                \
            e1 = *(const float4v*)(rp + ge1);                      \
            o1 = *(const float4v*)(rp + go1);                      \
        }                                                          \
    } while (0)

#define WRITE_ROW(sb) do {                                         \
        char* wb0 = (sb) + (1 + 4 * w40) * PIX_STRIDE + cp0 * 4;   \
        *(unsigned*)(wb0                  ) = pack2(e0[0], o0[0]); \
        *(unsigned*)(wb0 +     PIX_STRIDE ) = pack2(e0[1], o0[1]); \
        *(unsigned*)(wb0 + 2 * PIX_STRIDE ) = pack2(e0[2], o0[2]); \
        *(unsigned*)(wb0 + 3 * PIX_STRIDE ) = pack2(e0[3], o0[3]); \
        if (has1) {                                                \
            char* wb1 = (sb) + (1 + 4 * w41) * PIX_STRIDE + cp1 * 4; \
            *(unsigned*)(wb1                  ) = pack2(e1[0], o1[0]); \
            *(unsigned*)(wb1 +     PIX_STRIDE ) = pack2(e1[1], o1[1]); \
            *(unsigned*)(wb1 + 2 * PIX_STRIDE ) = pack2(e1[2], o1[2]); \
            *(unsigned*)(wb1 + 3 * PIX_STRIDE ) = pack2(e1[3], o1[3]); \
        }                                                          \
        if (tid < 8) {  /* zero the two w-halo pixels (px 0 and 225) */ \
            int px = (tid < 4) ? 0 : (RING_PX - 1);                \
            *(short8*)((sb) + px * PIX_STRIDE + (tid & 3) * 16) = z8; \
        }                                                          \
    } while (0)

#define ZERO_ROW(sb) do {                                          \
        for (int i = tid; i < ROW_BYTES / 16; i += NTHR)           \
            *(short8*)((sb) + i * 16) = z8;                        \
    } while (0)

    // ===== Prologue: fill ring with rows h1-1, h1, h1+1 =====
#pragma unroll
    for (int j = 0; j < 3; ++j) {
        int hh = h1 - 1 + j;
        char* sb = (j == 0) ? ring0 : (j == 1) ? ring1 : ring2;
        if (hh >= 0 && hh < HH) {   // block-uniform
            LOAD_ROW(hh);
            WRITE_ROW(sb);
        } else {
            ZERO_ROW(sb);
        }
    }
    __syncthreads();   // one full drain at prologue is fine

    // ===== Main loop: rA = row h-1, rB = h, rC = h+1; write h+2 over rA =====
    char *rA = ring0, *rB = ring1, *rC = ring2;
    const int pcol = col * PIX_STRIDE + khalf * 16;

    for (int h = h1; h < h1 + STRIPE; ++h) {
        const int hh = h + 2;
        const bool do_pref = (hh <= h1 + STRIPE);   // last needed row = h1+STRIPE
        const bool validrow = do_pref && (hh < HH); // block-uniform

        // Phase 1: issue next row's global loads (vmcnt tracked to use in Phase 4)
        if (validrow) LOAD_ROW(hh);

        // Phase 2: compute output row h; wave w owns px [32w, 32w+32)
        if (wid < 7) {
            const int px0 = wid * 32;
            f32x16 acc = biasv;   // bias folded into accumulator init
            const int pb = px0 * PIX_STRIDE + pcol;
#pragma unroll
            for (int rs = 0; rs < 9; ++rs) {
                const int r = rs / 3, s = rs - 3 * r;
                const char* rb = (r == 0) ? rA : (r == 1) ? rB : rC;
                const int addr = pb + s * PIX_STRIDE;
#pragma unroll
                for (int ch = 0; ch < 2; ++ch) {
                    short8 bfrag = *(const short8*)(rb + addr + ch * 32);
                    acc = __builtin_amdgcn_mfma_f32_32x32x16_bf16(
                        wfrag[rs * 2 + ch], bfrag, acc, 0, 0, 0);
                }
            }
            const int ybase = n * C_OUT * HW + h * WW + px0 + col;
#pragma unroll
            for (int i = 0; i < 16; ++i) {
                int ko = (i & 3) + 8 * (i >> 2) + 4 * khalf;
                Y[ybase + ko * HW] = acc[i];   // fire-and-forget: never drained
            }
        }

        // Barrier #1: LDS reads of rA retired (consumed by MFMAs); no vmcnt drain
        BAR();

        // Phase 4: convert + write row h+2 into the expired slot
        if (validrow) {
            WRITE_ROW(rA);
        } else if (do_pref) {
            ZERO_ROW(rA);   // image bottom edge
        }
        // Barrier #2: ds_writes visible (lgkmcnt only); Y stores still in flight
        BAR();

        // rotate ring
        char* t = rA; rA = rB; rB = rC; rC = t;
    }
#undef LOAD_ROW
#undef WRITE_ROW
#undef ZERO_ROW
}

extern "C" void kernel_launch(void* const* d_in, const int* in_sizes, int n_in,
                              void* d_out, int out_size, void* d_ws, size_t ws_size,
                              hipStream_t stream) {
    const float* X = (const float*)d_in[0];
    const float* W = (const float*)d_in[1];
    const float* B = (const float*)d_in[2];
    float* Y = (float*)d_out;
    // 256 blocks = 32 images x 8 stripes; 1 block/CU (LDS 54.2KB, VGPR 116)
    conv3x3_rows<<<dim3(256), dim3(NTHR), 0, stream>>>(X, W, B, Y);
}

// Round 14
// 99.385 us; speedup vs baseline: 2.2246x; 1.0306x over previous
//
#include <hip/hip_runtime.h>

typedef __attribute__((ext_vector_type(4))) float float4v;
typedef __attribute__((ext_vector_type(4))) float f32x4;
typedef __attribute__((ext_vector_type(8))) short short8;
typedef __attribute__((ext_vector_type(16))) float f32x16;

#define C_IN 32
#define C_OUT 32
#define HH 224
#define WW 224
#define HW (HH * WW)
#define STRIPE 14                 // 16 stripes x 32 imgs = 512 blocks -> 2 blocks/CU
#define RING_PX 226               // w = -1 .. 224 (halo columns at px 0 and 225)
#define PIX_STRIDE 80             // 64B data (32ch bf16) + 16B pad; conflict-free b128
#define ROW_BYTES (RING_PX * PIX_STRIDE)  // 18,080
#define NTHR 512

// fp32 -> bf16 bits, round-to-nearest-even
__device__ __forceinline__ short f2bf(float f) {
    unsigned u = __float_as_uint(f);
    u += 0x7FFFu + ((u >> 16) & 1u);
    return (short)(u >> 16);
}
__device__ __forceinline__ unsigned pack2(float e, float o) {
    return (unsigned)(unsigned short)f2bf(e) | ((unsigned)(unsigned short)f2bf(o) << 16);
}

// LDS-visibility-only barrier (no vmcnt drain; R13 verified correct & clean).
// The "memory" clobber also blocks LICM from hoisting the (h-invariant) W/bias
// LDS reads out of the row loop into 72+ persistent regs.
#define BAR() do {                                             \
        asm volatile("s_waitcnt lgkmcnt(0)" ::: "memory");     \
        __builtin_amdgcn_s_barrier();                          \
    } while (0)

// R14: make 4 waves/SIMD reachable. Every prior attempt (R7/R11/R12) died on
// register arithmetic: persistent wfrag(72)+acc(16)+bias(16)+staging > the 128
// unified VGPR+AGPR cap of 4 waves/EU -> spill -> void experiment. Fix: W and
// bias live in LDS (18.4KB + 128B; identical per-lane frags for all waves,
// contiguous b128 = conflict-free), no persistent prefetch (R8/R9/R13: worthless).
// Peak pressure ~110 < 128. waves_per_eu(4,4) + 2 blocks/CU (LDS 72.8KB x2):
// blocks slide phases independently -> P4 load latency hides under the other
// block's compute. This is the cross-block TLP test, attempt #4.
__global__ __launch_bounds__(NTHR) __attribute__((amdgpu_waves_per_eu(4, 4)))
void conv3x3_rows(const float* __restrict__ X, const float* __restrict__ Wt,
                  const float* __restrict__ Bias, float* __restrict__ Y) {
    __shared__ __align__(16) char ring0[ROW_BYTES];
    __shared__ __align__(16) char ring1[ROW_BYTES];
    __shared__ __align__(16) char ring2[ROW_BYTES];   // 54,240 B
    __shared__ __align__(16) char wlds[18 * 1024];    // 18,432 B: frag(rs,ch) x 64 lanes x 16B
    __shared__ __align__(16) float blds[32];          // bias in C-frag order, per khalf

    const int tid = threadIdx.x;
    const int lane = tid & 63;
    const int wid = tid >> 6;      // wave 0..7
    const int col = lane & 31;     // A: out-channel; B/C: pixel col
    const int khalf = lane >> 5;   // K-half of MFMA K=16 slice

    // --- Prologue A: wave 0 writes W fragments to LDS (identical for all waves) ---
    if (tid < 64) {
#pragma unroll
        for (int rs = 0; rs < 9; ++rs) {
#pragma unroll
            for (int ch = 0; ch < 2; ++ch) {
                short8 f;
#pragma unroll
                for (int j = 0; j < 8; ++j) {
                    int c = ch * 16 + (tid >> 5) * 8 + j;
                    f[j] = f2bf(Wt[((tid & 31) * C_IN + c) * 9 + rs]);  // W[k_out][c][r][s]
                }
                *(short8*)(wlds + (rs * 2 + ch) * 1024 + tid * 16) = f;
            }
        }
    }
    // bias in C-fragment order: blds[kh*16 + i] = Bias[(i&3) + 8*(i>>2) + 4*kh]
    if (tid < 32) {
        int kh = tid >> 4, i = tid & 15;
        blds[tid] = Bias[(i & 3) + 8 * (i >> 2) + 4 * kh];
    }

    // --- Staging geometry: unit u = w4*16 + cp (cp = channel-pair, w4 = 4px group) ---
    const int cp0 = tid & 15, w40 = tid >> 4;         // unit0 = tid (896 units)
    const int t1 = tid + NTHR;
    const bool has1 = (tid < 896 - NTHR);             // threads 0..383 take 2nd unit
    const int cp1 = t1 & 15, w41 = t1 >> 4;
    const int ge0 = (2 * cp0) * HW + 4 * w40;         // float offsets from (n,hh) row base
    const int go0 = ge0 + HW;
    const int ge1 = (2 * cp1) * HW + 4 * w41;
    const int go1 = ge1 + HW;

    const int bid = blockIdx.x;
    const int n = bid >> 4;                // image
    const int h1 = (bid & 15) * STRIPE;    // stripe start row
    const float* Xn = X + n * C_IN * HW;

    const short8 z8 = {0, 0, 0, 0, 0, 0, 0, 0};

    // Load + convert + LDS-write one input row (transient regs only; no prefetch)
#define STAGE_ROW(hh, sb) do {                                     \
        const float* rp = Xn + (hh) * WW;                          \
        float4v e0 = *(const float4v*)(rp + ge0);                  \
        float4v o0 = *(const float4v*)(rp + go0);                  \
        float4v e1, o1;                                            \
        if (has1) {                                                \
            e1 = *(const float4v*)(rp + ge1);                      \
            o1 = *(const float4v*)(rp + go1);                      \
        }                                                          \
        char* wb0 = (sb) + (1 + 4 * w40) * PIX_STRIDE + cp0 * 4;   \
        *(unsigned*)(wb0                  ) = pack2(e0[0], o0[0]); \
        *(unsigned*)(wb0 +     PIX_STRIDE ) = pack2(e0[1], o0[1]); \
        *(unsigned*)(wb0 + 2 * PIX_STRIDE ) = pack2(e0[2], o0[2]); \
        *(unsigned*)(wb0 + 3 * PIX_STRIDE ) = pack2(e0[3], o0[3]); \
        if (has1) {                                                \
            char* wb1 = (sb) + (1 + 4 * w41) * PIX_STRIDE + cp1 * 4; \
            *(unsigned*)(wb1                  ) = pack2(e1[0], o1[0]); \
            *(unsigned*)(wb1 +     PIX_STRIDE ) = pack2(e1[1], o1[1]); \
            *(unsigned*)(wb1 + 2 * PIX_STRIDE ) = pack2(e1[2], o1[2]); \
            *(unsigned*)(wb1 + 3 * PIX_STRIDE ) = pack2(e1[3], o1[3]); \
        }                                                          \
        if (tid < 8) {  /* zero the two w-halo pixels (px 0 and 225) */ \
            int px = (tid < 4) ? 0 : (RING_PX - 1);                \
            *(short8*)((sb) + px * PIX_STRIDE + (tid & 3) * 16) = z8; \
        }                                                          \
    } while (0)

#define ZERO_ROW(sb) do {                                          \
        for (int i = tid; i < ROW_BYTES / 16; i += NTHR)           \
            *(short8*)((sb) + i * 16) = z8;                        \
    } while (0)

    // --- Prologue B: fill ring with rows h1-1, h1, h1+1 ---
#pragma unroll
    for (int j = 0; j < 3; ++j) {
        int hh = h1 - 1 + j;
        char* sb = (j == 0) ? ring0 : (j == 1) ? ring1 : ring2;
        if (hh >= 0) {   // block-uniform; hh <= 211 < 224 always
            STAGE_ROW(hh, sb);
        } else {
            ZERO_ROW(sb);
        }
    }
    __syncthreads();   // full drain once at prologue

    // ===== Main loop: rA = row h-1, rB = h, rC = h+1; stage h+2 over rA =====
    char *rA = ring0, *rB = ring1, *rC = ring2;
    const int pcol = col * PIX_STRIDE + khalf * 16;

    for (int h = h1; h < h1 + STRIPE; ++h) {
        const int hh = h + 2;
        const bool do_pref = (hh <= h1 + STRIPE);   // last needed row = h1+STRIPE
        const bool validrow = do_pref && (hh < HH); // block-uniform

        // P2: compute output row h; wave w owns px [32w, 32w+32)
        if (wid < 7) {
            const int px0 = wid * 32;
            // acc init from bias LDS (broadcast reads, 4 x b128)
            f32x16 acc;
#pragma unroll
            for (int j = 0; j < 4; ++j) {
                f32x4 bb = *(const f32x4*)(blds + khalf * 16 + j * 4);
#pragma unroll
                for (int k = 0; k < 4; ++k) acc[j * 4 + k] = bb[k];
            }
            const int pb = px0 * PIX_STRIDE + pcol;
#pragma unroll
            for (int rs = 0; rs < 9; ++rs) {
                const int r = rs / 3, s = rs - 3 * r;
                const char* rb = (r == 0) ? rA : (r == 1) ? rB : rC;
                const int addr = pb + s * PIX_STRIDE;
#pragma unroll
                for (int ch = 0; ch < 2; ++ch) {
                    short8 wf = *(const short8*)(wlds + (rs * 2 + ch) * 1024 + lane * 16);
                    short8 bf = *(const short8*)(rb + addr + ch * 32);
                    acc = __builtin_amdgcn_mfma_f32_32x32x16_bf16(wf, bf, acc, 0, 0, 0);
                }
            }
            const int ybase = n * C_OUT * HW + h * WW + px0 + col;
#pragma unroll
            for (int i = 0; i < 16; ++i) {
                int ko = (i & 3) + 8 * (i >> 2) + 4 * khalf;
                Y[ybase + ko * HW] = acc[i];   // fire-and-forget
            }
        }

        // Barrier #1: ring reads retired before rA overwrite (lgkmcnt only)
        BAR();

        // P4: stage row h+2 into the expired slot (loads exposed here;
        // covered by the OTHER resident block's compute — the TLP bet)
        if (validrow) {
            STAGE_ROW(hh, rA);
        } else if (do_pref) {
            ZERO_ROW(rA);   // image bottom edge
        }
        // Barrier #2: ds_writes visible
        BAR();

        // rotate ring
        char* t = rA; rA = rB; rB = rC; rC = t;
    }
#undef STAGE_ROW
#undef ZERO_ROW
}

extern "C" void kernel_launch(void* const* d_in, const int* in_sizes, int n_in,
                              void* d_out, int out_size, void* d_ws, size_t ws_size,
                              hipStream_t stream) {
    const float* X = (const float*)d_in[0];
    const float* W = (const float*)d_in[1];
    const float* B = (const float*)d_in[2];
    float* Y = (float*)d_out;
    // 512 blocks = 32 images x 16 stripes; 2 resident per CU (LDS 72.8KB x 2)
    conv3x3_rows<<<dim3(512), dim3(NTHR), 0, stream>>>(X, W, B, Y);
}

// Round 15
// 78.905 us; speedup vs baseline: 2.8020x; 1.2596x over previous
//
#include <hip/hip_runtime.h>

typedef __attribute__((ext_vector_type(4))) float float4v;
typedef __attribute__((ext_vector_type(4))) float f32x4;
typedef __attribute__((ext_vector_type(8))) short short8;
typedef __attribute__((ext_vector_type(16))) float f32x16;

#define C_IN 32
#define C_OUT 32
#define HH 224
#define WW 224
#define HW (HH * WW)
#define STRIPE 28                 // 8 stripes x 32 imgs = 256 blocks, 1/CU
#define RING_PX 226               // w = -1 .. 224 (halo columns at px 0 and 225)
#define PIX_STRIDE 80             // 64B data (32ch bf16) + 16B pad; conflict-free b128
#define ROW_BYTES (RING_PX * PIX_STRIDE)  // 18,080
#define NTHR 512

// fp32 -> bf16 bits, round-to-nearest-even
__device__ __forceinline__ short f2bf(float f) {
    unsigned u = __float_as_uint(f);
    u += 0x7FFFu + ((u >> 16) & 1u);
    return (short)(u >> 16);
}
__device__ __forceinline__ unsigned pack2(float e, float o) {
    return (unsigned)(unsigned short)f2bf(e) | ((unsigned)(unsigned short)f2bf(o) << 16);
}

// LDS-visibility-only barrier (R13-verified). No vmcnt drain in the main loop.
#define BAR() do {                                             \
        asm volatile("s_waitcnt lgkmcnt(0)" ::: "memory");     \
        __builtin_amdgcn_s_barrier();                          \
    } while (0)

// R15: attack the one invariant left. Every plateau round (R6/R8/R13/R14) wrote
// Y at exactly ~2.0 TB/s — scattered 128B chunks into 16 plane-strided regions,
// L2-eviction-ordered at HBM (row-thrash), AND Y evicts X from the 256MB L3
// (FETCH ~110MB = X re-streamed from HBM). Fix = shape the HBM write stream:
// (1) retile acc through ybuf[32][224] in LDS -> 1KB-contiguous plane-row
// stores; (2) nontemporal stores -> bypass L2, preserve issue-order contiguity
// at HBM, and leave L3 to X (X becomes L3-resident).
__global__ __launch_bounds__(NTHR) __attribute__((amdgpu_waves_per_eu(4, 4)))
void conv3x3_rows(const float* __restrict__ X, const float* __restrict__ Wt,
                  const float* __restrict__ Bias, float* __restrict__ Y) {
    __shared__ __align__(16) char ring0[ROW_BYTES];
    __shared__ __align__(16) char ring1[ROW_BYTES];
    __shared__ __align__(16) char ring2[ROW_BYTES];   // 54,240 B
    __shared__ __align__(16) char wlds[18 * 1024];    // 18,432 B: frag(rs,ch) x 64 lanes x 16B
    __shared__ __align__(16) float blds[32];          // bias in C-frag order
    __shared__ __align__(16) float ybuf[C_OUT * WW];  // 28,672 B output-row retile
    // total LDS: 101,472 B -> 1 block/CU (R14: 2 blocks == 1 block anyway)

    const int tid = threadIdx.x;
    const int lane = tid & 63;
    const int wid = tid >> 6;      // wave 0..7
    const int col = lane & 31;     // A: out-channel; B/C: pixel col
    const int khalf = lane >> 5;   // K-half of MFMA K=16 slice

    // --- Prologue A: wave 0 writes W fragments + bias to LDS ---
    if (tid < 64) {
#pragma unroll
        for (int rs = 0; rs < 9; ++rs) {
#pragma unroll
            for (int ch = 0; ch < 2; ++ch) {
                short8 f;
#pragma unroll
                for (int j = 0; j < 8; ++j) {
                    int c = ch * 16 + (tid >> 5) * 8 + j;
                    f[j] = f2bf(Wt[((tid & 31) * C_IN + c) * 9 + rs]);  // W[k_out][c][r][s]
                }
                *(short8*)(wlds + (rs * 2 + ch) * 1024 + tid * 16) = f;
            }
        }
    }
    if (tid < 32) {
        int kh = tid >> 4, i = tid & 15;
        blds[tid] = Bias[(i & 3) + 8 * (i >> 2) + 4 * kh];
    }

    // --- Staging geometry: unit u = w4*16 + cp ---
    const int cp0 = tid & 15, w40 = tid >> 4;
    const int t1 = tid + NTHR;
    const bool has1 = (tid < 896 - NTHR);
    const int cp1 = t1 & 15, w41 = t1 >> 4;
    const int ge0 = (2 * cp0) * HW + 4 * w40;
    const int go0 = ge0 + HW;
    const int ge1 = (2 * cp1) * HW + 4 * w41;
    const int go1 = ge1 + HW;

    const int bid = blockIdx.x;
    const int n = bid >> 3;
    const int h1 = (bid & 7) * STRIPE;
    const float* Xn = X + n * C_IN * HW;

    const short8 z8 = {0, 0, 0, 0, 0, 0, 0, 0};

#define STAGE_ROW(hh, sb) do {                                     \
        const float* rp = Xn + (hh) * WW;                          \
        float4v e0 = *(const float4v*)(rp + ge0);                  \
        float4v o0 = *(const float4v*)(rp + go0);                  \
        float4v e1, o1;                                            \
        if (has1) {                                                \
            e1 = *(const float4v*)(rp + ge1);                      \
            o1 = *(const float4v*)(rp + go1);                      \
        }                                                          \
        char* wb0 = (sb) + (1 + 4 * w40) * PIX_STRIDE + cp0 * 4;   \
        *(unsigned*)(wb0                  ) = pack2(e0[0], o0[0]); \
        *(unsigned*)(wb0 +     PIX_STRIDE ) = pack2(e0[1], o0[1]); \
        *(unsigned*)(wb0 + 2 * PIX_STRIDE ) = pack2(e0[2], o0[2]); \
        *(unsigned*)(wb0 + 3 * PIX_STRIDE ) = pack2(e0[3], o0[3]); \
        if (has1) {                                                \
            char* wb1 = (sb) + (1 + 4 * w41) * PIX_STRIDE + cp1 * 4; \
            *(unsigned*)(wb1                  ) = pack2(e1[0], o1[0]); \
            *(unsigned*)(wb1 +     PIX_STRIDE ) = pack2(e1[1], o1[1]); \
            *(unsigned*)(wb1 + 2 * PIX_STRIDE ) = pack2(e1[2], o1[2]); \
            *(unsigned*)(wb1 + 3 * PIX_STRIDE ) = pack2(e1[3], o1[3]); \
        }                                                          \
        if (tid < 8) {  /* zero the two w-halo pixels (px 0 and 225) */ \
            int px = (tid < 4) ? 0 : (RING_PX - 1);                \
            *(short8*)((sb) + px * PIX_STRIDE + (tid & 3) * 16) = z8; \
        }                                                          \
    } while (0)

#define ZERO_ROW(sb) do {                                          \
        for (int i = tid; i < ROW_BYTES / 16; i += NTHR)           \
            *(short8*)((sb) + i * 16) = z8;                        \
    } while (0)

    // --- Prologue B: fill ring with rows h1-1, h1, h1+1 ---
#pragma unroll
    for (int j = 0; j < 3; ++j) {
        int hh = h1 - 1 + j;
        char* sb = (j == 0) ? ring0 : (j == 1) ? ring1 : ring2;
        if (hh >= 0) {   // block-uniform; hh <= 198 < 224 always
            STAGE_ROW(hh, sb);
        } else {
            ZERO_ROW(sb);
        }
    }
    __syncthreads();   // full drain once at prologue

    // ===== Main loop =====
    char *rA = ring0, *rB = ring1, *rC = ring2;
    const int pcol = col * PIX_STRIDE + khalf * 16;

    for (int h = h1; h < h1 + STRIPE; ++h) {
        const int hh = h + 2;
        const bool do_pref = (hh <= h1 + STRIPE);
        const bool validrow = do_pref && (hh < HH); // block-uniform

        // P2: compute output row h; acc lands in ybuf (LDS), not global
        if (wid < 7) {
            const int px0 = wid * 32;
            f32x16 acc;
#pragma unroll
            for (int j = 0; j < 4; ++j) {
                f32x4 bb = *(const f32x4*)(blds + khalf * 16 + j * 4);
#pragma unroll
                for (int k = 0; k < 4; ++k) acc[j * 4 + k] = bb[k];
            }
            const int pb = px0 * PIX_STRIDE + pcol;
#pragma unroll
            for (int rs = 0; rs < 9; ++rs) {
                const int r = rs / 3, s = rs - 3 * r;
                const char* rb = (r == 0) ? rA : (r == 1) ? rB : rC;
                const int addr = pb + s * PIX_STRIDE;
#pragma unroll
                for (int ch = 0; ch < 2; ++ch) {
                    short8 wf = *(const short8*)(wlds + (rs * 2 + ch) * 1024 + lane * 16);
                    short8 bf = *(const short8*)(rb + addr + ch * 32);
                    acc = __builtin_amdgcn_mfma_f32_32x32x16_bf16(wf, bf, acc, 0, 0, 0);
                }
            }
            // retile: ybuf[ko][px] (half-waves 896 words apart = same banks, 2-way = free)
            const int px = px0 + col;
#pragma unroll
            for (int i = 0; i < 16; ++i) {
                int ko = (i & 3) + 8 * (i >> 2) + 4 * khalf;
                ybuf[ko * WW + px] = acc[i];
            }
        }

        // Barrier #1: ybuf writes visible; ring rA reads retired (lgkmcnt only)
        BAR();

        // P3a: flush ybuf -> Y as 1KB-contiguous nontemporal stores.
        // unit u = ko*56 + seg (seg = 16B segment of the 896B plane-row);
        // consecutive lanes walk a plane-row sequentially -> HBM sees
        // issue-ordered 896B bursts per plane (nt bypasses L2 reordering).
        {
            float* Yr = Y + n * C_OUT * HW + h * WW;
#pragma unroll
            for (int it = 0; it < 4; ++it) {
                int u = tid + it * NTHR;          // 0..2047; 1792 used
                if (u < C_OUT * 56) {
                    f32x4 v = *(const f32x4*)(ybuf + u * 4);
                    int ko = u / 56, rem = u - ko * 56;
                    __builtin_nontemporal_store(v, (float4v*)(Yr + ko * HW + rem * 4));
                }
            }
        }

        // P3b: stage row h+2 into the expired ring slot
        if (validrow) {
            STAGE_ROW(hh, rA);
        } else if (do_pref) {
            ZERO_ROW(rA);   // image bottom edge
        }

        // Barrier #2: ring writes visible; ybuf reads retired before next P2
        BAR();

        // rotate ring
        char* t = rA; rA = rB; rB = rC; rC = t;
    }
#undef STAGE_ROW
#undef ZERO_ROW
}

extern "C" void kernel_launch(void* const* d_in, const int* in_sizes, int n_in,
                              void* d_out, int out_size, void* d_ws, size_t ws_size,
                              hipStream_t stream) {
    const float* X = (const float*)d_in[0];
    const float* W = (const float*)d_in[1];
    const float* B = (const float*)d_in[2];
    float* Y = (float*)d_out;
    // 256 blocks = 32 images x 8 stripes; 1 block/CU (LDS 101.5KB)
    conv3x3_rows<<<dim3(256), dim3(NTHR), 0, stream>>>(X, W, B, Y);
}

// Round 16
// 78.303 us; speedup vs baseline: 2.8236x; 1.0077x over previous
//
#include <hip/hip_runtime.h>

typedef __attribute__((ext_vector_type(4))) float float4v;
typedef __attribute__((ext_vector_type(4))) float f32x4;
typedef __attribute__((ext_vector_type(8))) short short8;
typedef __attribute__((ext_vector_type(16))) float f32x16;

#define C_IN 32
#define C_OUT 32
#define HH 224
#define WW 224
#define HW (HH * WW)
#define STRIPE 28                 // 8 stripes x 32 imgs = 256 blocks, 1/CU
#define RING_PX 226               // w = -1 .. 224 (halo columns at px 0 and 225)
#define PIX_STRIDE 80             // 64B data (32ch bf16) + 16B pad; conflict-free b128
#define ROW_BYTES (RING_PX * PIX_STRIDE)  // 18,080
#define NTHR 512

// fp32 -> bf16 bits, round-to-nearest-even
__device__ __forceinline__ short f2bf(float f) {
    unsigned u = __float_as_uint(f);
    u += 0x7FFFu + ((u >> 16) & 1u);
    return (short)(u >> 16);
}
__device__ __forceinline__ unsigned pack2(float e, float o) {
    return (unsigned)(unsigned short)f2bf(e) | ((unsigned)(unsigned short)f2bf(o) << 16);
}

// LDS-visibility-only barrier (R13-verified). No vmcnt drain in the main loop.
#define BAR() do {                                             \
        asm volatile("s_waitcnt lgkmcnt(0)" ::: "memory");     \
        __builtin_amdgcn_s_barrier();                          \
    } while (0)

// R16 = R15 (write-stream shaping: ybuf retile + nt stores, the 23% win) with
// the remaining per-row overhead collapsed: ONE barrier per row.
//   ring-of-4 (slot = row & 3): compute reads slots (h-1,h,h+1)&3, stage writes
//     (h+2)&3 — disjoint within a step; slot (h+2)&3's last reader (row h-2)
//     was step h-1, fenced by that step's end barrier.
//   double ybuf: flush reads ybuf[(h-1)&1], compute writes ybuf[h&1] — disjoint;
//     flush(h-1) vs compute(h-1)'s writes fenced by end-of-(h-1) barrier;
//     compute(h) reuses the buffer flushed in step h-1, same fence.
// Flush + compute + stage now interleave in one phase (ds/VMEM/MFMA co-issue),
// one lgkm drain + rendezvous per row instead of two.
__global__ __launch_bounds__(NTHR) __attribute__((amdgpu_waves_per_eu(4, 4)))
void conv3x3_rows(const float* __restrict__ X, const float* __restrict__ Wt,
                  const float* __restrict__ Bias, float* __restrict__ Y) {
    __shared__ __align__(16) char ring[4 * ROW_BYTES];   // 72,320 B
    __shared__ __align__(16) char wlds[18 * 1024];       // 18,432 B
    __shared__ __align__(16) float blds[32];
    __shared__ __align__(16) float ybuf0[C_OUT * WW];    // 28,672 B
    __shared__ __align__(16) float ybuf1[C_OUT * WW];    // 28,672 B
    // total 148,224 B -> 1 block/CU

    const int tid = threadIdx.x;
    const int lane = tid & 63;
    const int wid = tid >> 6;      // wave 0..7
    const int col = lane & 31;     // A: out-channel; B/C: pixel col
    const int khalf = lane >> 5;   // K-half of MFMA K=16 slice

    // --- Prologue A: wave 0 writes W fragments + bias to LDS ---
    if (tid < 64) {
#pragma unroll
        for (int rs = 0; rs < 9; ++rs) {
#pragma unroll
            for (int ch = 0; ch < 2; ++ch) {
                short8 f;
#pragma unroll
                for (int j = 0; j < 8; ++j) {
                    int c = ch * 16 + (tid >> 5) * 8 + j;
                    f[j] = f2bf(Wt[((tid & 31) * C_IN + c) * 9 + rs]);  // W[k_out][c][r][s]
                }
                *(short8*)(wlds + (rs * 2 + ch) * 1024 + tid * 16) = f;
            }
        }
    }
    if (tid < 32) {
        int kh = tid >> 4, i = tid & 15;
        blds[tid] = Bias[(i & 3) + 8 * (i >> 2) + 4 * kh];
    }

    // --- Staging geometry: unit u = w4*16 + cp ---
    const int cp0 = tid & 15, w40 = tid >> 4;
    const int t1 = tid + NTHR;
    const bool has1 = (tid < 896 - NTHR);
    const int cp1 = t1 & 15, w41 = t1 >> 4;
    const int ge0 = (2 * cp0) * HW + 4 * w40;
    const int go0 = ge0 + HW;
    const int ge1 = (2 * cp1) * HW + 4 * w41;
    const int go1 = ge1 + HW;

    const int bid = blockIdx.x;
    const int n = bid >> 3;
    const int h1 = (bid & 7) * STRIPE;
    const float* Xn = X + n * C_IN * HW;
    float* Yn = Y + n * C_OUT * HW;

    const short8 z8 = {0, 0, 0, 0, 0, 0, 0, 0};

#define STAGE_ROW(hh, sb) do {                                     \
        const float* rp = Xn + (hh) * WW;                          \
        float4v e0 = *(const float4v*)(rp + ge0);                  \
        float4v o0 = *(const float4v*)(rp + go0);                  \
        float4v e1, o1;                                            \
        if (has1) {                                                \
            e1 = *(const float4v*)(rp + ge1);                      \
            o1 = *(const float4v*)(rp + go1);                      \
        }                                                          \
        char* wb0 = (sb) + (1 + 4 * w40) * PIX_STRIDE + cp0 * 4;   \
        *(unsigned*)(wb0                  ) = pack2(e0[0], o0[0]); \
        *(unsigned*)(wb0 +     PIX_STRIDE ) = pack2(e0[1], o0[1]); \
        *(unsigned*)(wb0 + 2 * PIX_STRIDE ) = pack2(e0[2], o0[2]); \
        *(unsigned*)(wb0 + 3 * PIX_STRIDE ) = pack2(e0[3], o0[3]); \
        if (has1) {                                                \
            char* wb1 = (sb) + (1 + 4 * w41) * PIX_STRIDE + cp1 * 4; \
            *(unsigned*)(wb1                  ) = pack2(e1[0], o1[0]); \
            *(unsigned*)(wb1 +     PIX_STRIDE ) = pack2(e1[1], o1[1]); \
            *(unsigned*)(wb1 + 2 * PIX_STRIDE ) = pack2(e1[2], o1[2]); \
            *(unsigned*)(wb1 + 3 * PIX_STRIDE ) = pack2(e1[3], o1[3]); \
        }                                                          \
        if (tid < 8) {  /* zero the two w-halo pixels (px 0 and 225) */ \
            int px = (tid < 4) ? 0 : (RING_PX - 1);                \
            *(short8*)((sb) + px * PIX_STRIDE + (tid & 3) * 16) = z8; \
        }                                                          \
    } while (0)

#define ZERO_ROW(sb) do {                                          \
        for (int i = tid; i < ROW_BYTES / 16; i += NTHR)           \
            *(short8*)((sb) + i * 16) = z8;                        \
    } while (0)

#define FLUSH_ROW(hf, yb) do {                                     \
        float* Yr = Yn + (hf) * WW;                                \
        _Pragma("unroll")                                          \
        for (int it = 0; it < 4; ++it) {                           \
            int u = tid + it * NTHR;                               \
            if (u < C_OUT * 56) {                                  \
                f32x4 v = *(const f32x4*)((yb) + u * 4);           \
                int ko = u / 56, rem = u - ko * 56;                \
                __builtin_nontemporal_store(v, (float4v*)(Yr + ko * HW + rem * 4)); \
            }                                                      \
        }                                                          \
    } while (0)

    // --- Prologue B: stage rows h1-1, h1, h1+1 into slots (row & 3) ---
#pragma unroll
    for (int j = 0; j < 3; ++j) {
        int hh = h1 - 1 + j;
        char* sb = ring + (hh & 3) * ROW_BYTES;   // (-1)&3 == 3
        if (hh >= 0) {   // block-uniform; hh <= 198 < 224 always
            STAGE_ROW(hh, sb);
        } else {
            ZERO_ROW(sb);
        }
    }
    __syncthreads();   // full drain once at prologue

    const int pcol = col * PIX_STRIDE + khalf * 16;

    // ===== Main loop: ONE barrier per row =====
    for (int h = h1; h < h1 + STRIPE; ++h) {
        const int hh = h + 2;
        const bool do_pref = (hh <= h1 + STRIPE);
        const bool validrow = do_pref && (hh < HH);  // block-uniform

        // P1: flush row h-1 from ybuf[(h-1)&1] (skip on first row of stripe)
        if (h > h1) {
            const float* yb = ((h - 1) & 1) ? ybuf1 : ybuf0;
            FLUSH_ROW(h - 1, yb);
        }

        // P2: compute row h -> ybuf[h&1] (LDS)
        if (wid < 7) {
            const int px0 = wid * 32;
            f32x16 acc;
#pragma unroll
            for (int j = 0; j < 4; ++j) {
                f32x4 bb = *(const f32x4*)(blds + khalf * 16 + j * 4);
#pragma unroll
                for (int k = 0; k < 4; ++k) acc[j * 4 + k] = bb[k];
            }
            const char* r0p = ring + ((h - 1) & 3) * ROW_BYTES;
            const char* r1p = ring + ((h    ) & 3) * ROW_BYTES;
            const char* r2p = ring + ((h + 1) & 3) * ROW_BYTES;
            const int pb = px0 * PIX_STRIDE + pcol;
#pragma unroll
            for (int rs = 0; rs < 9; ++rs) {
                const int r = rs / 3, s = rs - 3 * r;
                const char* rb = (r == 0) ? r0p : (r == 1) ? r1p : r2p;
                const int addr = pb + s * PIX_STRIDE;
#pragma unroll
                for (int ch = 0; ch < 2; ++ch) {
                    short8 wf = *(const short8*)(wlds + (rs * 2 + ch) * 1024 + lane * 16);
                    short8 bf = *(const short8*)(rb + addr + ch * 32);
                    acc = __builtin_amdgcn_mfma_f32_32x32x16_bf16(wf, bf, acc, 0, 0, 0);
                }
            }
            float* yb = (h & 1) ? ybuf1 : ybuf0;
            const int px = px0 + col;
#pragma unroll
            for (int i = 0; i < 16; ++i) {
                int ko = (i & 3) + 8 * (i >> 2) + 4 * khalf;
                yb[ko * WW + px] = acc[i];
            }
        }

        // P3: stage row h+2 into slot (h+2)&3 (last read as row h-2 in step h-1)
        if (validrow) {
            STAGE_ROW(hh, ring + (hh & 3) * ROW_BYTES);
        } else if (do_pref) {
            ZERO_ROW(ring + (hh & 3) * ROW_BYTES);   // image bottom edge
        }

        // The ONLY barrier: fences ybuf writes (flush next step), ring writes
        // (compute next step), and ring/ybuf reads (overwrites next step).
        BAR();
    }

    // Epilogue: flush the stripe's last row (barrier above fenced its ybuf writes)
    {
        const int hl = h1 + STRIPE - 1;
        const float* yb = (hl & 1) ? ybuf1 : ybuf0;
        FLUSH_ROW(hl, yb);
    }
#undef STAGE_ROW
#undef ZERO_ROW
#undef FLUSH_ROW
}

extern "C" void kernel_launch(void* const* d_in, const int* in_sizes, int n_in,
                              void* d_out, int out_size, void* d_ws, size_t ws_size,
                              hipStream_t stream) {
    const float* X = (const float*)d_in[0];
    const float* W = (const float*)d_in[1];
    const float* B = (const float*)d_in[2];
    float* Y = (float*)d_out;
    // 256 blocks = 32 images x 8 stripes; 1 block/CU (LDS 148.2KB)
    conv3x3_rows<<<dim3(256), dim3(NTHR), 0, stream>>>(X, W, B, Y);
}